// Round 11
// baseline (138.602 us; speedup 1.0000x reference)
//
#include <hip/hip_runtime.h>
#include <hip/hip_bf16.h>

#define D_IN  768
#define D_E   256
#define M_TOT 512      // B*S
#define E_TOT 100000

typedef __attribute__((ext_vector_type(4))) float f32x4;
typedef __attribute__((ext_vector_type(8))) short bf16x8;

__device__ __forceinline__ unsigned short bf16bits(float f) {
    union { __hip_bfloat16 h; unsigned short u; } c;
    c.h = __float2bfloat16(f);
    return c.u;
}

__device__ __forceinline__ void gload_lds16(const void* g, void* l) {
    __builtin_amdgcn_global_load_lds(
        (const __attribute__((address_space(1))) void*)g,
        (__attribute__((address_space(3))) void*)l, 16, 0, 0);
}

// ---------------------------------------------------------------------------
// Fused prep+proj (unchanged from round 9/10 — at BW floor):
//   blocks [0,64):    proj  qb[m][e] = bf16(tanh(x@W^T+b)/||row||)
//   blocks [64,1627): prep  eb[n][k] = bf16(en[n][k]/||en[n]||)
// ---------------------------------------------------------------------------
#define PROJ_BLOCKS 64
#define PREP_BLOCKS 1563                 // 1563*64 = 100032 >= 100000
#define PP_GRID (PROJ_BLOCKS + PREP_BLOCKS)
#define PTM 8
#define PBK 64
#define PROUNDS (D_IN / PBK)             // 12

__global__ __launch_bounds__(512) void fused_pp(
    const float* __restrict__ x, const float* __restrict__ W,
    const float* __restrict__ b, const float* __restrict__ en,
    unsigned short* __restrict__ qb, unsigned short* __restrict__ eb)
{
    __shared__ float ws[D_E * (PBK + 1)];   // 65 KB (proj only)
    __shared__ float xs[PTM][PBK];
    __shared__ float red[PTM][4];
    __shared__ float qiv[PTM];

    const int t   = threadIdx.x;
    const int bid = blockIdx.x;

    if (bid >= PROJ_BLOCKS) {
        const int lane = t & 63;
        const int gw   = (bid - PROJ_BLOCKS) * 8 + (t >> 6);
        #pragma unroll 2
        for (int i = 0; i < 8; ++i) {
            const int row = gw * 8 + i;
            if (row >= E_TOT) break;
            const float4 v = *reinterpret_cast<const float4*>(
                en + (size_t)row * D_E + lane * 4);
            float s = v.x*v.x + v.y*v.y + v.z*v.z + v.w*v.w;
            #pragma unroll
            for (int off = 1; off < 64; off <<= 1) s += __shfl_xor(s, off, 64);
            const float sc = 1.0f / fmaxf(sqrtf(s), 1e-8f);
            union { unsigned short u[4]; uint2 d; } o;
            o.u[0] = bf16bits(v.x * sc); o.u[1] = bf16bits(v.y * sc);
            o.u[2] = bf16bits(v.z * sc); o.u[3] = bf16bits(v.w * sc);
            *reinterpret_cast<uint2*>(eb + (size_t)row * D_E + lane * 4) = o.d;
        }
        return;
    }

    const int m0   = bid * PTM;
    const int e    = t & 255;
    const int half = t >> 8;
    const int c4   = t & 15;
    const int rr   = t >> 4;

    float4 wreg[8];
    float  xreg = 0.f;
    float  acc[4] = {0.f, 0.f, 0.f, 0.f};

    #pragma unroll
    for (int i = 0; i < 8; ++i)
        wreg[i] = *reinterpret_cast<const float4*>(
            &W[(size_t)(i * 32 + rr) * D_IN + c4 * 4]);
    xreg = x[(size_t)(m0 + (t >> 6)) * D_IN + (t & 63)];

    for (int rd = 0; rd < PROUNDS; ++rd) {
        #pragma unroll
        for (int i = 0; i < 8; ++i) {
            float* dst = &ws[(i * 32 + rr) * (PBK + 1) + c4 * 4];
            dst[0] = wreg[i].x; dst[1] = wreg[i].y;
            dst[2] = wreg[i].z; dst[3] = wreg[i].w;
        }
        xs[t >> 6][t & 63] = xreg;
        __syncthreads();
        if (rd + 1 < PROUNDS) {
            const int k0 = (rd + 1) * PBK;
            #pragma unroll
            for (int i = 0; i < 8; ++i)
                wreg[i] = *reinterpret_cast<const float4*>(
                    &W[(size_t)(i * 32 + rr) * D_IN + k0 + c4 * 4]);
            xreg = x[(size_t)(m0 + (t >> 6)) * D_IN + k0 + (t & 63)];
        }
        #pragma unroll
        for (int k = 0; k < PBK; ++k) {
            const float wv = ws[e * (PBK + 1) + k];
            #pragma unroll
            for (int j = 0; j < 4; ++j)
                acc[j] = fmaf(xs[half * 4 + j][k], wv, acc[j]);
        }
        __syncthreads();
    }

    const float bias = b[e];
    const int wv4 = (t >> 6) & 3;
    const int lane = t & 63;
    float q[4];
    #pragma unroll
    for (int j = 0; j < 4; ++j) {
        q[j] = tanhf(acc[j] + bias);
        float s = q[j] * q[j];
        #pragma unroll
        for (int off = 1; off < 64; off <<= 1) s += __shfl_xor(s, off, 64);
        if (lane == 0) red[half * 4 + j][wv4] = s;
    }
    __syncthreads();
    if (t < PTM) {
        const float s = red[t][0] + red[t][1] + red[t][2] + red[t][3];
        qiv[t] = 1.0f / fmaxf(sqrtf(s), 1e-8f);
    }
    __syncthreads();
    #pragma unroll
    for (int j = 0; j < 4; ++j)
        qb[(size_t)(m0 + half * 4 + j) * D_E + e] =
            bf16bits(q[j] * qiv[half * 4 + j]);
}

// ---------------------------------------------------------------------------
// Kernel 2 (v11): q panel in REGISTERS (loaded once from LDS -> cannot be
// rematerialized, unlike r4/r5's global loads), entity tiles TRIPLE-buffered
// (stage 2 ahead; stores get ~3 tile periods to drain via in-order vmcnt).
// Hot loop per ks: 2 ds_read_b128 + 4 MFMA. LDS = 64 (q) + 3x32 (e) = 160 KiB.
// vmcnt ladder: tile0=4, tile1=8, steady=12 (op counts kept wave-uniform).
// ---------------------------------------------------------------------------
#define BM 128
#define BN 64
#define TPB 25
#define NGRPN 63                        // 63*25*64 = 100800 >= 100000
#define SIM_GRID (NGRPN * (M_TOT / BM))   // 252

__device__ __forceinline__ void stage_etile(
    const unsigned short* __restrict__ eb, int n0, unsigned short* dst, int t)
{
    #pragma unroll
    for (int i = 0; i < 4; ++i) {
        const int c   = i * 512 + t;
        const int row = c >> 5;             // 0..63
        const int c16 = c & 31;
        int rg = n0 + row;
        if (rg >= E_TOT) rg = E_TOT - 1;    // clamp: uniform 4 ops always
        const unsigned short* src =
            eb + (size_t)rg * D_E + ((c16 ^ (row & 7)) << 3);
        gload_lds16(src, (void*)&dst[(size_t)c << 3]);
    }
}

__global__ __launch_bounds__(512, 2) void sim_kernel(
    const unsigned short* __restrict__ eb, const unsigned short* __restrict__ qb,
    float* __restrict__ out)
{
    __shared__ unsigned short qs[BM * D_E];       // 64 KB
    __shared__ unsigned short es[3][BN * D_E];    // 3 x 32 KB  (total 160 KiB)

    const int t    = threadIdx.x;
    const int lane = t & 63;
    const int wid  = t >> 6;        // 0..7
    const int l15  = lane & 15;
    const int lk   = lane >> 4;     // 0..3
    const int wm   = (wid >> 1) * 32;   // 0,32,64,96
    const int wn   = (wid & 1) * 32;    // 0,32

    int vbid;
    {
        const int q = SIM_GRID >> 3, r = SIM_GRID & 7;   // 31, 4
        const int xcd = blockIdx.x & 7, rk = blockIdx.x >> 3;
        vbid = (xcd < r ? xcd * (q + 1) : r * (q + 1) + (xcd - r) * q) + rk;
    }
    const int mg    = vbid & 3;
    const int ngrp  = vbid >> 2;            // 0..62
    const int m0    = mg * BM;
    const int nbase = ngrp * (TPB * BN);    // ngrp * 1600

    // ---- prologue: stage q (8 ops) + entity tiles 0,1 (4+4 ops) ----
    #pragma unroll
    for (int i = 0; i < 8; ++i) {
        const int c   = i * 512 + t;
        const int row = c >> 5;             // 0..127
        const int c16 = c & 31;
        const unsigned short* src =
            qb + (size_t)(m0 + row) * D_E + ((c16 ^ (row & 7)) << 3);
        gload_lds16(src, (void*)&qs[(size_t)c << 3]);
    }
    stage_etile(eb, nbase,      &es[0][0], t);
    stage_etile(eb, nbase + BN, &es[1][0], t);

    // wait q staged (e0,e1 stay in flight), then load q panel into registers
    asm volatile("s_waitcnt vmcnt(8)" ::: "memory");
    __builtin_amdgcn_s_barrier();
    __builtin_amdgcn_sched_barrier(0);

    const char* qsb = reinterpret_cast<const char*>(qs);
    bf16x8 qf[2][8];
    #pragma unroll
    for (int mf = 0; mf < 2; ++mf) {
        const int rq = wm + mf * 16 + l15;
        #pragma unroll
        for (int ks = 0; ks < 8; ++ks) {
            const int cbq = (ks * 64 + lk * 16) ^ ((rq & 7) << 4);
            qf[mf][ks] = *reinterpret_cast<const bf16x8*>(qsb + rq * 512 + cbq);
        }
    }

    int cur = 0;
    for (int tt = 0; tt < TPB; ++tt) {
        const int n0 = nbase + tt * BN;
        if (n0 >= E_TOT) break;             // block-uniform

        // this tile's stage retired; older stores also retired (in-order);
        // newest ops (next stage + last stores) stay in flight.
        if (tt == 0)      asm volatile("s_waitcnt vmcnt(4)"  ::: "memory");
        else if (tt == 1) asm volatile("s_waitcnt vmcnt(8)"  ::: "memory");
        else              asm volatile("s_waitcnt vmcnt(12)" ::: "memory");
        __builtin_amdgcn_s_barrier();
        __builtin_amdgcn_sched_barrier(0);

        // stage tile tt+2 into the buffer 2 ahead (always 4 ops, clamped)
        int nx = cur + 2; if (nx >= 3) nx -= 3;
        stage_etile(eb, n0 + 2 * BN, &es[nx][0], t);

        const char* esb = reinterpret_cast<const char*>(&es[cur][0]);

        f32x4 acc[2][2];
        #pragma unroll
        for (int mf = 0; mf < 2; ++mf)
            #pragma unroll
            for (int nf = 0; nf < 2; ++nf)
                acc[mf][nf] = (f32x4){0.f, 0.f, 0.f, 0.f};

        __builtin_amdgcn_s_setprio(1);
        #pragma unroll
        for (int ks = 0; ks < 8; ++ks) {
            const int kb = ks * 64 + lk * 16;
            bf16x8 ef[2];
            #pragma unroll
            for (int nf = 0; nf < 2; ++nf) {
                const int row = wn + nf * 16 + l15;
                const int cb  = kb ^ ((row & 7) << 4);
                ef[nf] = *reinterpret_cast<const bf16x8*>(esb + row * 512 + cb);
            }
            #pragma unroll
            for (int mf = 0; mf < 2; ++mf) {
                acc[mf][0] = __builtin_amdgcn_mfma_f32_16x16x32_bf16(
                    ef[0], qf[mf][ks], acc[mf][0], 0, 0, 0);
                acc[mf][1] = __builtin_amdgcn_mfma_f32_16x16x32_bf16(
                    ef[1], qf[mf][ks], acc[mf][1], 0, 0, 0);
            }
        }
        __builtin_amdgcn_s_setprio(0);

        // stores: never waited on; ~3 tile periods to drain (triple buffer)
        #pragma unroll
        for (int mf = 0; mf < 2; ++mf) {
            const int m = m0 + wm + mf * 16 + l15;
            #pragma unroll
            for (int nf = 0; nf < 2; ++nf) {
                const int n = n0 + wn + nf * 16 + lk * 4;
                if (n < E_TOT)
                    *reinterpret_cast<f32x4*>(&out[(size_t)m * E_TOT + n]) =
                        acc[mf][nf];
            }
        }

        cur = (cur + 1 == 3) ? 0 : cur + 1;
    }
}

// ---------------------------------------------------------------------------
extern "C" void kernel_launch(void* const* d_in, const int* in_sizes, int n_in,
                              void* d_out, int out_size, void* d_ws, size_t ws_size,
                              hipStream_t stream) {
    const float* x  = (const float*)d_in[0];   // [4,128,768]
    const float* W  = (const float*)d_in[1];   // [256,768]
    const float* b  = (const float*)d_in[2];   // [256]
    const float* en = (const float*)d_in[3];   // [100000,256]
    float* out = (float*)d_out;                // [512,100000]

    unsigned short* qb = (unsigned short*)d_ws;                 // 256 KB
    unsigned short* eb = (unsigned short*)((char*)d_ws + (size_t)M_TOT * D_E * 2);

    fused_pp<<<PP_GRID, 512, 0, stream>>>(x, W, b, en, qb, eb); // 1627 blocks
    sim_kernel<<<SIM_GRID, 512, 0, stream>>>(eb, qb, out);      // 252 blocks
}